// Round 3
// baseline (110.987 us; speedup 1.0000x reference)
//
#include <hip/hip_runtime.h>
#include <stdint.h>

// Grouped GEMM a[16384,512] x b[8][512,512] (fp32) -> out fp32, two-phase:
//   P1a: A fp32 -> bf16 (row-major, same layout)
//   P1b: B [g][k][n] fp32 -> bf16 [g][n][k] (transposed via LDS tile)
//   P2 : m97-style GEMM: 128x128 tile, BK=64, global_load_lds 16B staging
//        (no VALU cvt / register round-trip in the K-loop), mfma 16x16x32 bf16.
// XCD swizzle: tm = (blk&7)*16 + ..., so each B[g] slice and each A row-group
// is read by blocks on one XCD -> L2-resident reuse (heuristic, perf-only).

#define KDIM 512
#define NDIM 512
#define BM 128
#define BN 128
#define BK 64

typedef __bf16 bf16x8 __attribute__((ext_vector_type(8)));
typedef __bf16 bf16x4 __attribute__((ext_vector_type(4)));
typedef float  f32x4  __attribute__((ext_vector_type(4)));

// ---------------- P1a: A fp32 -> bf16, 8 elems/thread ----------------
__global__ __launch_bounds__(256)
void cvtA_kernel(const float* __restrict__ A, __bf16* __restrict__ Abf) {
    const size_t i = ((size_t)blockIdx.x * 256 + threadIdx.x) * 8;
    f32x4 v0 = *(const f32x4*)(A + i);
    f32x4 v1 = *(const f32x4*)(A + i + 4);
    bf16x8 w;
    w[0] = (__bf16)v0[0]; w[1] = (__bf16)v0[1]; w[2] = (__bf16)v0[2]; w[3] = (__bf16)v0[3];
    w[4] = (__bf16)v1[0]; w[5] = (__bf16)v1[1]; w[6] = (__bf16)v1[2]; w[7] = (__bf16)v1[3];
    *(bf16x8*)(Abf + i) = w;
}

// ---------------- P1b: B [g][k][n] -> bf16 [g][n][k], 64x64 LDS tiles ----
#define TSTRIDE 68
__global__ __launch_bounds__(256)
void cvtB_kernel(const float* __restrict__ B, __bf16* __restrict__ Bt) {
    __shared__ __bf16 tile[64 * TSTRIDE];
    const int bid = blockIdx.x;
    const int g  = bid >> 6;
    const int kt = (bid >> 3) & 7;
    const int nt = bid & 7;
    const int k0 = kt * 64, n0 = nt * 64;
    const int t = threadIdx.x;

    // read coalesced along n, cvt, store [k][n] into LDS
    const int rk = (t >> 4) * 4;
    const int rn = (t & 15) * 4;
#pragma unroll
    for (int dk = 0; dk < 4; ++dk) {
        f32x4 v = *(const f32x4*)(B + (size_t)(g * KDIM + k0 + rk + dk) * NDIM + n0 + rn);
        bf16x4 w;
        w[0] = (__bf16)v[0]; w[1] = (__bf16)v[1]; w[2] = (__bf16)v[2]; w[3] = (__bf16)v[3];
        *(bf16x4*)&tile[(rk + dk) * TSTRIDE + rn] = w;
    }
    __syncthreads();
    // gather columns, write coalesced along k
    const int on = t >> 2;
    const int kc = (t & 3) * 16;
    bf16x8 o0, o1;
#pragma unroll
    for (int j = 0; j < 8; ++j) o0[j] = tile[(kc + j) * TSTRIDE + on];
#pragma unroll
    for (int j = 0; j < 8; ++j) o1[j] = tile[(kc + 8 + j) * TSTRIDE + on];
    __bf16* dst = Bt + (size_t)(g * NDIM + n0 + on) * KDIM + k0 + kc;
    *(bf16x8*)dst = o0;
    *(bf16x8*)(dst + 8) = o1;
}

// ---------------- P2: bf16 GEMM with global_load_lds staging -------------
__global__ __launch_bounds__(256)
void gemm_kernel(const __bf16* __restrict__ Abf, const __bf16* __restrict__ Bt,
                 const int* __restrict__ glist, float* __restrict__ C, int G) {
    __shared__ __bf16 As[BM * BK];   // [row][k], stride 64 (lds-dma layout)
    __shared__ __bf16 Bs[BN * BK];   // [n][k],   stride 64

    const int b   = blockIdx.x;
    const int nTM = gridDim.x >> 2;
    int tm, tn;
    if ((nTM & 7) == 0) {            // XCD-aware: blk%8 -> XCD (round-robin)
        const int per = nTM >> 3;
        const int xcd = b & 7;
        const int i   = b >> 3;
        tm = xcd * per + (i >> 2);
        tn = i & 3;
    } else {
        tm = b >> 2;
        tn = b & 3;
    }
    const int row0 = tm * BM;
    const int col0 = tn * BN;

    int gid = 0;
    for (int g = 0; g < G; ++g) gid += (glist[g] <= row0) ? 1 : 0;
    const __bf16* Bg = Bt + (size_t)gid * NDIM * KDIM;

    const int t    = threadIdx.x;
    const int lane = t & 63;
    const int wave = t >> 6;
    const int lm   = lane & 15;
    const int quad = lane >> 4;
    const int wm   = wave >> 1;
    const int wn   = wave & 1;

    const int srow = lane >> 3;        // 0..7 row within 8-row chunk
    const int scol = (lane & 7) * 8;   // k element offset (16 B)

    f32x4 acc[4][4];
#pragma unroll
    for (int i = 0; i < 4; ++i)
#pragma unroll
        for (int j = 0; j < 4; ++j)
            acc[i][j] = (f32x4){0.f, 0.f, 0.f, 0.f};

    for (int it = 0; it < KDIM / BK; ++it) {
        const int kb = it * BK;
        // ---- stage A (128x64) + B (128x64) bf16 via 16B lds-DMA ----
#pragma unroll
        for (int s = 0; s < 4; ++s) {
            const int row = wave * 32 + s * 8 + srow;
            __builtin_amdgcn_global_load_lds(
                (const __attribute__((address_space(1))) void*)
                    (Abf + (size_t)(row0 + row) * KDIM + kb + scol),
                (__attribute__((address_space(3))) void*)(As + row * BK + scol),
                16, 0, 0);
            __builtin_amdgcn_global_load_lds(
                (const __attribute__((address_space(1))) void*)
                    (Bg + (size_t)(col0 + row) * KDIM + kb + scol),
                (__attribute__((address_space(3))) void*)(Bs + row * BK + scol),
                16, 0, 0);
        }
        __syncthreads();

        // ---- 2 k-steps x 16 MFMAs ----
#pragma unroll
        for (int ks = 0; ks < 2; ++ks) {
            const int g16 = ks * 4 + quad;
            bf16x8 af[4], bfr[4];
#pragma unroll
            for (int i = 0; i < 4; ++i)
                af[i] = *(const bf16x8*)&As[(wm * 64 + i * 16 + lm) * BK + g16 * 8];
#pragma unroll
            for (int j = 0; j < 4; ++j)
                bfr[j] = *(const bf16x8*)&Bs[(wn * 64 + j * 16 + lm) * BK + g16 * 8];
#pragma unroll
            for (int i = 0; i < 4; ++i)
#pragma unroll
                for (int j = 0; j < 4; ++j)
                    acc[i][j] = __builtin_amdgcn_mfma_f32_16x16x32_bf16(
                        af[i], bfr[j], acc[i][j], 0, 0, 0);
        }
        __syncthreads();
    }

    // ---- epilogue: C/D layout col=lane&15, row=quad*4+reg ----
#pragma unroll
    for (int i = 0; i < 4; ++i) {
        const int gr0 = row0 + wm * 64 + i * 16 + quad * 4;
#pragma unroll
        for (int j = 0; j < 4; ++j) {
            const int gc = col0 + wn * 64 + j * 16 + lm;
#pragma unroll
            for (int r = 0; r < 4; ++r)
                C[(size_t)(gr0 + r) * NDIM + gc] = acc[i][j][r];
        }
    }
}

extern "C" void kernel_launch(void* const* d_in, const int* in_sizes, int n_in,
                              void* d_out, int out_size, void* d_ws, size_t ws_size,
                              hipStream_t stream) {
    const float* a  = (const float*)d_in[0];
    const float* bw = (const float*)d_in[1];
    const int*   gl = (const int*)d_in[2];
    float* out = (float*)d_out;

    const int M = in_sizes[0] / KDIM;          // 16384
    const int G = in_sizes[2];                 // 8

    __bf16* Abf = (__bf16*)d_ws;                                   // M*K bf16
    __bf16* Bt  = (__bf16*)((char*)d_ws + (size_t)M * KDIM * 2);   // G*N*K bf16

    cvtA_kernel<<<M * (KDIM / 8) / 256, 256, 0, stream>>>(a, Abf);
    cvtB_kernel<<<G * 64, 256, 0, stream>>>(bw, Bt);
    gemm_kernel<<<(M / BM) * (NDIM / BN), 256, 0, stream>>>(Abf, Bt, gl, out, G);
}